// Round 8
// baseline (140.651 us; speedup 1.0000x reference)
//
#include <hip/hip_runtime.h>

// Shapes (fixed by the problem)
#define B_ 2
#define S_ 2048
#define D_ 1024
#define H_ 16
#define HS_ 64
#define HD_ 1024     // H_*HS_
#define BS_ (B_*S_)  // 4096 flattened rows
#define BK_ 64       // K-tile depth for kv_mfma
#define BKO_ 128     // K-tile depth for out_mfma
#define TP_ 136      // padded row length (elems) for transposed LDS tiles

typedef __attribute__((ext_vector_type(8))) short short8_t;   // 8 bf16 (MFMA A/B frag)
typedef __attribute__((ext_vector_type(4))) float float4_t;   // MFMA C/D frag

__device__ inline unsigned short f32_to_bf16(float f) {
  unsigned int u = __float_as_uint(f);
  u += 0x7FFF + ((u >> 16) & 1);   // round-to-nearest-even
  return (unsigned short)(u >> 16);
}

// async global->LDS, 16B per lane. LDS dest is wave-uniform base + lane*16.
__device__ inline void async_copy16(const void* g, void* lds) {
  __builtin_amdgcn_global_load_lds(
      (const __attribute__((address_space(1))) void*)g,
      (__attribute__((address_space(3))) void*)lds, 16, 0, 0);
}

// XOR swizzle: LDS[row][phys chunk c] holds global chunk c ^ (row&7).
// Frag read of logical chunk q from row R -> phys q ^ (R&7); across a 16-lane
// group R&7 sweeps 8 values -> 32 banks covered, 2 lanes/bank = free (m136).

// ---------------------------------------------------------------------------
// prep: blocks [0,4096) convert x fp32->bf16 (4 elems/thread);
// blocks [4096,4352) build Wkvt[h][128][d] bf16 (rows 0-63 = Wk cols,
// rows 64-127 = Wv cols), k(d)-contiguous for kv_mfma B staging.
// ---------------------------------------------------------------------------
__global__ __launch_bounds__(256) void prep_kernel(
    const float* __restrict__ x, const float* __restrict__ Wk,
    const float* __restrict__ Wv, unsigned short* __restrict__ xb,
    unsigned short* __restrict__ Wkvt) {
  const int blk = blockIdx.x;
  const int tid = threadIdx.x;
  __shared__ float lds[64][65];
  if (blk < 4096) {
    int idx = blk * 256 + tid;
    float4 v = ((const float4*)x)[idx];
    ushort4 o;
    o.x = f32_to_bf16(v.x); o.y = f32_to_bf16(v.y);
    o.z = f32_to_bf16(v.z); o.w = f32_to_bf16(v.w);
    ((ushort4*)xb)[idx] = o;
    return;
  }
  const int wblk = blk - 4096;
  const int h = wblk >> 4;
  const int d0 = (wblk & 15) * 64;
  // K half
#pragma unroll
  for (int i = 0; i < 16; ++i) {
    int idx = tid + i * 256; int dd = idx >> 6, e = idx & 63;
    lds[e][dd] = Wk[((size_t)h * D_ + d0 + dd) * HS_ + e];
  }
  __syncthreads();
#pragma unroll
  for (int i = 0; i < 16; ++i) {
    int idx = tid + i * 256; int e = idx >> 6, dd = idx & 63;
    Wkvt[((size_t)h * 128 + e) * D_ + d0 + dd] = f32_to_bf16(lds[e][dd]);
  }
  __syncthreads();
  // V half
#pragma unroll
  for (int i = 0; i < 16; ++i) {
    int idx = tid + i * 256; int dd = idx >> 6, e = idx & 63;
    lds[e][dd] = Wv[((size_t)h * D_ + d0 + dd) * HS_ + e];
  }
  __syncthreads();
#pragma unroll
  for (int i = 0; i < 16; ++i) {
    int idx = tid + i * 256; int e = idx >> 6, dd = idx & 63;
    Wkvt[((size_t)h * 128 + 64 + e) * D_ + d0 + dd] = f32_to_bf16(lds[e][dd]);
  }
}

// ---------------------------------------------------------------------------
// kv_mfma (fused, fat tile): per (stile, head-pair):
//   phase 1: [128 s x 256 (K0|V0|K1|V1)] = x-tile @ Wkvt rows [hp*256, +256)
//            512 threads = 8 waves as 2(m) x 4(n); A-frags shared across 2
//            heads -> CU staging 2.6x lower than 128x128 pairs.
//   phase 2: LDS-transpose K,V per head -> Mpart[stile][h] = K^T V via MFMA;
//            V written to Vb for out_mfma. K never touches global memory.
// grid = 32 * 8 = 256 blocks, 512 threads.
// ---------------------------------------------------------------------------
__global__ __launch_bounds__(512) void kv_mfma_kernel(
    const unsigned short* __restrict__ xb,    // [4096][1024]
    const unsigned short* __restrict__ Wkvt,  // [2048][1024] flattened
    unsigned short* __restrict__ Vb,          // [4096][1024]
    float* __restrict__ Mpart) {              // [32][16][64][64]
  const int blk = blockIdx.x;
  const int stile = blk & 31;
  const int hp = blk >> 5;                   // head pair 0..7
  const int s0 = stile * 128;
  const int tid = threadIdx.x;
  const int lane = tid & 63;
  const int wid = tid >> 6;                  // 0..7
  const int wm = wid & 1, wn = wid >> 1;     // wn 0..3
  const int quad = lane >> 4, l16 = lane & 15;
  const int srow8 = lane >> 3;               // 0..7: row within 8-row group
  const int csw = ((lane & 7) ^ srow8) * 8;  // swizzled chunk (elems)
  const int xa = l16 & 7;                    // frag-read swizzle key

  // Aliased LDS: phase 1 A(16 KB)+B(32 KB); phase 2 four 64xTP_ tiles (68 KB).
  __shared__ __align__(16) unsigned char smem[4 * 64 * TP_ * 2];
  unsigned short* As = (unsigned short*)smem;                     // [128][64]
  unsigned short* Bs = (unsigned short*)(smem + 128 * BK_ * 2);   // [256][64]
  // Transposed-tile base i (0..3 = K0,V0,K1,V1) computed at point of use:
  // (unsigned short*)(smem + i * 64 * TP_ * 2)

  float4_t acc[4][4];
  const float4_t fz = {0.f, 0.f, 0.f, 0.f};
#pragma unroll
  for (int i = 0; i < 4; ++i)
#pragma unroll
    for (int j = 0; j < 4; ++j) acc[i][j] = fz;

  const unsigned short* Bpanel = Wkvt + (size_t)hp * 256 * D_;
  for (int k0 = 0; k0 < D_; k0 += BK_) {
#pragma unroll
    for (int i = 0; i < 2; ++i) {            // A: 16 groups of 8 rows
      int g = wid * 2 + i;
      int r = g * 8 + srow8;
      async_copy16(xb + (size_t)(s0 + r) * D_ + k0 + csw, As + g * 8 * BK_);
    }
#pragma unroll
    for (int i = 0; i < 4; ++i) {            // B: 32 groups of 8 rows
      int g = wid * 4 + i;
      int r = g * 8 + srow8;
      async_copy16(Bpanel + (size_t)r * D_ + k0 + csw, Bs + g * 8 * BK_);
    }
    __syncthreads();
    short8_t a[4][2], b[4][2];
#pragma unroll
    for (int mi = 0; mi < 4; ++mi)
#pragma unroll
      for (int ks = 0; ks < 2; ++ks)
        a[mi][ks] = *(const short8_t*)(As + (wm * 64 + mi * 16 + l16) * BK_ +
                                       ((ks * 4 + quad) ^ xa) * 8);
#pragma unroll
    for (int ni = 0; ni < 4; ++ni)
#pragma unroll
      for (int ks = 0; ks < 2; ++ks)
        b[ni][ks] = *(const short8_t*)(Bs + (wn * 64 + ni * 16 + l16) * BK_ +
                                       ((ks * 4 + quad) ^ xa) * 8);
#pragma unroll
    for (int ks = 0; ks < 2; ++ks)
#pragma unroll
      for (int mi = 0; mi < 4; ++mi)
#pragma unroll
        for (int ni = 0; ni < 4; ++ni)
          acc[mi][ni] = __builtin_amdgcn_mfma_f32_16x16x32_bf16(
              a[mi][ks], b[ni][ks], acc[mi][ni], 0, 0, 0);
    __syncthreads();
  }

  // ---- phase 2a: dump quadrants transposed into LDS (bf16) ----
  // C cols: wn0 = K(head0), wn1 = V(head0), wn2 = K(head1), wn3 = V(head1).
  {
    unsigned short* dstT = (unsigned short*)(smem + (size_t)wn * 64 * TP_ * 2);
#pragma unroll
    for (int mi = 0; mi < 4; ++mi)
#pragma unroll
      for (int ni = 0; ni < 4; ++ni) {
        int f = ni * 16 + l16;
        int sm = wm * 64 + mi * 16 + quad * 4;
        ushort4 o;
        o.x = f32_to_bf16(acc[mi][ni][0]);
        o.y = f32_to_bf16(acc[mi][ni][1]);
        o.z = f32_to_bf16(acc[mi][ni][2]);
        o.w = f32_to_bf16(acc[mi][ni][3]);
        *(ushort4*)&dstT[f * TP_ + sm] = o;
      }
  }
  __syncthreads();

  // ---- phase 2b: Vb[s0+s][hp*128 + col] from Vtl tiles (16B stores) ----
#pragma unroll
  for (int u = 0; u < 4; ++u) {
    int unit = tid + u * 512;            // 0..2047 = 128 s x 16 e-chunks
    int s = unit & 127;
    int ec = unit >> 7;                  // 0..15
    int hd = ec >> 3;                    // which head's V
    const unsigned short* vt =
        (const unsigned short*)(smem + (size_t)(hd * 2 + 1) * 64 * TP_ * 2);
    union { unsigned short u16[8]; uint4 v; } t;
#pragma unroll
    for (int e = 0; e < 8; ++e) t.u16[e] = vt[((ec & 7) * 8 + e) * TP_ + s];
    *(uint4*)&Vb[(size_t)(s0 + s) * HD_ + hp * 128 + hd * 64 + (ec & 7) * 8] = t.v;
  }

  // ---- phase 2c: Mpart[f][e] = sum_{s<128} K[s,f] V[s,e] via MFMA ----
  // waves 0-3: head0 (f-range (wid&3)*16); waves 4-7: head1.
  {
    const int hd = wid >> 2;
    const int fw = (wid & 3) * 16;
    const unsigned short* Ktl =
        (const unsigned short*)(smem + (size_t)(hd * 2) * 64 * TP_ * 2);
    const unsigned short* Vtl =
        (const unsigned short*)(smem + (size_t)(hd * 2 + 1) * 64 * TP_ * 2);
    float4_t macc[4];
#pragma unroll
    for (int ni = 0; ni < 4; ++ni) macc[ni] = fz;
#pragma unroll
    for (int ss = 0; ss < 4; ++ss) {     // 4 k-steps of 32 s
      short8_t ka = *(const short8_t*)&Ktl[(fw + l16) * TP_ + ss * 32 + quad * 8];
#pragma unroll
      for (int ni = 0; ni < 4; ++ni) {
        short8_t vv = *(const short8_t*)&Vtl[(ni * 16 + l16) * TP_ + ss * 32 + quad * 8];
        macc[ni] = __builtin_amdgcn_mfma_f32_16x16x32_bf16(ka, vv, macc[ni], 0, 0, 0);
      }
    }
    float* mdst = Mpart + ((size_t)stile * H_ + hp * 2 + hd) * 4096;
#pragma unroll
    for (int ni = 0; ni < 4; ++ni) {
      int e = ni * 16 + l16;
#pragma unroll
      for (int r = 0; r < 4; ++r) {
        int f = fw + quad * 4 + r;
        mdst[f * 64 + e] = macc[ni][r];
      }
    }
  }
}

// ---------------------------------------------------------------------------
// m_reduce: M[b,h] = 0.125 * sum over the 16 stiles of batch b. 128 blocks.
// ---------------------------------------------------------------------------
__global__ __launch_bounds__(256) void m_reduce_kernel(
    const float* __restrict__ Mpart, float* __restrict__ M) {
  const int gid = blockIdx.x * 256 + threadIdx.x;
  const int e0 = gid * 4;               // [0, 131072)
  const int bh = e0 >> 12;              // b*16+h
  const int idx = e0 & 4095;
  const int b = bh >> 4, h = bh & 15;
  float4 s = {0.f, 0.f, 0.f, 0.f};
#pragma unroll
  for (int p = 0; p < 16; ++p) {
    const float4 v =
        *(const float4*)&Mpart[(((size_t)(b * 16 + p)) * H_ + h) * 4096 + idx];
    s.x += v.x; s.y += v.y; s.z += v.z; s.w += v.w;
  }
  s.x *= 0.125f; s.y *= 0.125f; s.z *= 0.125f; s.w *= 0.125f;
  *(float4*)&M[(size_t)bh * 4096 + idx] = s;
}

// ---------------------------------------------------------------------------
// p_kernel: P[b][h*64+f][d] = sum_e M[b,h,f,e]*Wproj[h*64+e][d], written
// TRANSPOSED as Pt[b][d][h*64+f] bf16 (k-contiguous for out_mfma staging).
// grid = B*H*(D/64) = 512 blocks.
// ---------------------------------------------------------------------------
__global__ __launch_bounds__(256) void p_kernel(
    const float* __restrict__ M, const float* __restrict__ Wproj,
    unsigned short* __restrict__ Pt) {
  const int blk = blockIdx.x;
  const int dtile = blk & 15;
  const int h = (blk >> 4) & 15;
  const int b = blk >> 8;
  const int d0 = dtile * 64;
  const int tid = threadIdx.x;
  const int tx = tid & 15, ty = tid >> 4;
  __shared__ float Ms[64][68];  // A: [e][f] (transposed on store)
  __shared__ float Ws[64][68];  // B: [e][d]
  const size_t mbase = ((size_t)(b * H_ + h)) * HS_ * HS_;
#pragma unroll
  for (int i = 0; i < 16; ++i) {
    int idx = tid + i * 256;
    int f = idx >> 6, e = idx & 63;
    Ms[e][f] = M[mbase + idx];
    Ws[f][e] = Wproj[(size_t)(h * HS_ + f) * D_ + d0 + e];
  }
  __syncthreads();
  float acc[4][4] = {};
#pragma unroll
  for (int kk = 0; kk < 64; ++kk) {
    const float4 a4 = *(const float4*)&Ms[kk][ty * 4];
    const float4 b4 = *(const float4*)&Ws[kk][tx * 4];
    const float a[4] = {a4.x, a4.y, a4.z, a4.w};
    const float bb[4] = {b4.x, b4.y, b4.z, b4.w};
#pragma unroll
    for (int i = 0; i < 4; ++i)
#pragma unroll
      for (int j = 0; j < 4; ++j) acc[i][j] += a[i] * bb[j];
  }
  // transpose through LDS: trans[d][f] then linear bf16 rows
  __syncthreads();
#pragma unroll
  for (int i = 0; i < 4; ++i)
#pragma unroll
    for (int j = 0; j < 4; ++j)
      Ms[tx * 4 + j][ty * 4 + i] = acc[i][j];
  __syncthreads();
  {
    int c = tid >> 2, ch = tid & 3;  // row c (d-dim), 16-elem chunk of f-dim
    unsigned short* dst = Pt + ((size_t)(b * D_ + d0 + c)) * HD_ + h * 64 + ch * 16;
#pragma unroll
    for (int e = 0; e < 16; ++e) dst[e] = f32_to_bf16(Ms[c][ch * 16 + e]);
  }
}

// ---------------------------------------------------------------------------
// out_mfma: out[s][d] = bproj[d] + sum_j Vb[s][j]*Pt[b][d][j].
// 128x128 tiles, 512 threads (8 waves as 2m x 4n, wave 64x32), BK=128,
// swizzled LDS. grid = 32*8 = 256 blocks.
// ---------------------------------------------------------------------------
__global__ __launch_bounds__(512) void out_mfma_kernel(
    const unsigned short* __restrict__ Vb,   // [4096][1024]
    const unsigned short* __restrict__ Pt,   // [2][1024][1024]
    const float* __restrict__ bproj,
    float* __restrict__ out) {
  const int blk = blockIdx.x;
  const int ntile = blk & 7;               // 1024/128 = 8
  const int stile = blk >> 3;              // 4096/128 = 32
  const int s0 = stile * 128;
  const int n0 = ntile * 128;
  const int b = s0 >> 11;
  const int tid = threadIdx.x;
  const int lane = tid & 63;
  const int wid = tid >> 6;                // 0..7
  const int wm = wid & 1, wn = wid >> 1;   // wn 0..3
  const int quad = lane >> 4, l16 = lane & 15;
  const int srow4 = lane >> 4;             // 4 rows per copy instr (256B rows)
  const int xa = l16 & 7;

  __shared__ __align__(16) unsigned short As[128 * BKO_];  // 32 KB
  __shared__ __align__(16) unsigned short Bs[128 * BKO_];  // 32 KB

  float4_t acc[4][2];
  const float4_t fz = {0.f, 0.f, 0.f, 0.f};
#pragma unroll
  for (int i = 0; i < 4; ++i)
#pragma unroll
    for (int j = 0; j < 2; ++j) acc[i][j] = fz;

  const unsigned short* Bpanel = Pt + (size_t)b * D_ * HD_;
  for (int k0 = 0; k0 < HD_; k0 += BKO_) {
#pragma unroll
    for (int i = 0; i < 4; ++i) {        // A: 32 groups of 4 rows
      int g = wid * 4 + i;
      int r = g * 4 + srow4;
      int ch = ((lane & 15) ^ (r & 7)) * 8;
      async_copy16(Vb + (size_t)(s0 + r) * HD_ + k0 + ch, As + g * 4 * BKO_);
    }
#pragma unroll
    for (int i = 0; i < 4; ++i) {        // B: 32 groups of 4 rows
      int g = wid * 4 + i;
      int r = g * 4 + srow4;
      int ch = ((lane & 15) ^ (r & 7)) * 8;
      async_copy16(Bpanel + (size_t)(n0 + r) * HD_ + k0 + ch, Bs + g * 4 * BKO_);
    }
    __syncthreads();
    short8_t a[4][4], bfr[2][4];
#pragma unroll
    for (int mi = 0; mi < 4; ++mi)
#pragma unroll
      for (int ks = 0; ks < 4; ++ks)
        a[mi][ks] = *(const short8_t*)(As + (wm * 64 + mi * 16 + l16) * BKO_ +
                                       ((ks * 4 + quad) ^ xa) * 8);
#pragma unroll
    for (int ni = 0; ni < 2; ++ni)
#pragma unroll
      for (int ks = 0; ks < 4; ++ks)
        bfr[ni][ks] = *(const short8_t*)(Bs + (wn * 32 + ni * 16 + l16) * BKO_ +
                                         ((ks * 4 + quad) ^ xa) * 8);
#pragma unroll
    for (int ks = 0; ks < 4; ++ks)
#pragma unroll
      for (int mi = 0; mi < 4; ++mi)
#pragma unroll
        for (int ni = 0; ni < 2; ++ni)
          acc[mi][ni] = __builtin_amdgcn_mfma_f32_16x16x32_bf16(
              a[mi][ks], bfr[ni][ks], acc[mi][ni], 0, 0, 0);
    __syncthreads();
  }
#pragma unroll
  for (int ni = 0; ni < 2; ++ni) {
    int col = n0 + wn * 32 + ni * 16 + l16;
    float bias = bproj[col];
#pragma unroll
    for (int mi = 0; mi < 4; ++mi) {
      int rowb = s0 + wm * 64 + mi * 16 + quad * 4;
#pragma unroll
      for (int r = 0; r < 4; ++r)
        out[(size_t)(rowb + r) * D_ + col] = acc[mi][ni][r] + bias;
    }
  }
}

extern "C" void kernel_launch(void* const* d_in, const int* in_sizes, int n_in,
                              void* d_out, int out_size, void* d_ws, size_t ws_size,
                              hipStream_t stream) {
  const float* x = (const float*)d_in[0];
  const float* Wk = (const float*)d_in[1];
  const float* Wv = (const float*)d_in[2];
  const float* Wproj = (const float*)d_in[3];
  const float* bproj = (const float*)d_in[4];
  float* out = (float*)d_out;

  // Workspace layout (~32.5 MB total); every element written before read.
  char* ws = (char*)d_ws;
  unsigned short* xb = (unsigned short*)ws;                  // 4M bf16 = 8 MB
  unsigned short* Wkvt = xb + (size_t)BS_ * D_;              // 2M bf16 = 4 MB
  unsigned short* Vb = Wkvt + (size_t)H_ * 128 * D_;         // 4M bf16 = 8 MB
  float* Mpart = (float*)(Vb + (size_t)BS_ * HD_);           // 2M f32 = 8 MB  [32][16][4096]
  float* M = Mpart + (size_t)32 * H_ * 4096;                 // 128K f32 = 0.5 MB
  unsigned short* Pt = (unsigned short*)(M + (size_t)B_ * H_ * 4096);  // 2M bf16 = 4 MB

  prep_kernel<<<dim3(4096 + H_ * (D_ / 64)), dim3(256), 0, stream>>>(x, Wk, Wv, xb, Wkvt);
  kv_mfma_kernel<<<dim3(32 * 8), dim3(512), 0, stream>>>(xb, Wkvt, Vb, Mpart);
  m_reduce_kernel<<<dim3(128), dim3(256), 0, stream>>>(Mpart, M);
  p_kernel<<<dim3(B_ * H_ * (D_ / 64)), dim3(256), 0, stream>>>(M, Wproj, Pt);
  out_mfma_kernel<<<dim3(32 * 8), dim3(512), 0, stream>>>(Vb, Pt, bproj, out);
}

// Round 9
// 132.283 us; speedup vs baseline: 1.0633x; 1.0633x over previous
//
#include <hip/hip_runtime.h>

// Shapes (fixed by the problem)
#define B_ 2
#define S_ 2048
#define D_ 1024
#define H_ 16
#define HS_ 64
#define HD_ 1024     // H_*HS_
#define BS_ (B_*S_)  // 4096 flattened rows
#define BK_ 128      // K-tile depth for kv_mfma (8 iters; 2 blocks/CU unchanged)
#define BKO_ 128     // K-tile depth for out_mfma
#define TP_ 136      // padded row length (elems) for transposed LDS tiles

typedef __attribute__((ext_vector_type(8))) short short8_t;   // 8 bf16 (MFMA A/B frag)
typedef __attribute__((ext_vector_type(4))) float float4_t;   // MFMA C/D frag

__device__ inline unsigned short f32_to_bf16(float f) {
  unsigned int u = __float_as_uint(f);
  u += 0x7FFF + ((u >> 16) & 1);   // round-to-nearest-even
  return (unsigned short)(u >> 16);
}

// async global->LDS, 16B per lane. LDS dest is wave-uniform base + lane*16.
__device__ inline void async_copy16(const void* g, void* lds) {
  __builtin_amdgcn_global_load_lds(
      (const __attribute__((address_space(1))) void*)g,
      (__attribute__((address_space(3))) void*)lds, 16, 0, 0);
}

// XOR swizzle (16-chunk rows): LDS[row][phys chunk c] holds global chunk
// (c&8) | ((c&7)^(row&7)). Frag read of logical chunk q from row R is at
// phys q ^ (R&7). Across a 16-lane group R&7 sweeps 8 values -> 32 banks
// covered, 2 lanes/bank = free (m136). Validated end-to-end in R6 out_mfma.

// ---------------------------------------------------------------------------
// prep: blocks [0,4096) convert x fp32->bf16 (4 elems/thread);
// blocks [4096,4352) build Wkvt[h][128][d] bf16 (rows 0-63 = Wk cols,
// rows 64-127 = Wv cols), k(d)-contiguous for kv_mfma B staging.
// ---------------------------------------------------------------------------
__global__ __launch_bounds__(256) void prep_kernel(
    const float* __restrict__ x, const float* __restrict__ Wk,
    const float* __restrict__ Wv, unsigned short* __restrict__ xb,
    unsigned short* __restrict__ Wkvt) {
  const int blk = blockIdx.x;
  const int tid = threadIdx.x;
  __shared__ float lds[64][65];
  if (blk < 4096) {
    int idx = blk * 256 + tid;
    float4 v = ((const float4*)x)[idx];
    ushort4 o;
    o.x = f32_to_bf16(v.x); o.y = f32_to_bf16(v.y);
    o.z = f32_to_bf16(v.z); o.w = f32_to_bf16(v.w);
    ((ushort4*)xb)[idx] = o;
    return;
  }
  const int wblk = blk - 4096;
  const int h = wblk >> 4;
  const int d0 = (wblk & 15) * 64;
  // K half
#pragma unroll
  for (int i = 0; i < 16; ++i) {
    int idx = tid + i * 256; int dd = idx >> 6, e = idx & 63;
    lds[e][dd] = Wk[((size_t)h * D_ + d0 + dd) * HS_ + e];
  }
  __syncthreads();
#pragma unroll
  for (int i = 0; i < 16; ++i) {
    int idx = tid + i * 256; int e = idx >> 6, dd = idx & 63;
    Wkvt[((size_t)h * 128 + e) * D_ + d0 + dd] = f32_to_bf16(lds[e][dd]);
  }
  __syncthreads();
  // V half
#pragma unroll
  for (int i = 0; i < 16; ++i) {
    int idx = tid + i * 256; int dd = idx >> 6, e = idx & 63;
    lds[e][dd] = Wv[((size_t)h * D_ + d0 + dd) * HS_ + e];
  }
  __syncthreads();
#pragma unroll
  for (int i = 0; i < 16; ++i) {
    int idx = tid + i * 256; int e = idx >> 6, dd = idx & 63;
    Wkvt[((size_t)h * 128 + 64 + e) * D_ + d0 + dd] = f32_to_bf16(lds[e][dd]);
  }
}

// ---------------------------------------------------------------------------
// kv_mfma (fused, R6 structure, BK=128): per (stile,h):
//   phase 1: [128 s x 128 (64 K | 64 V)] = x-tile @ Wkvt_h, 8 K-iters.
//   phase 2: LDS-transpose K,V -> Mpart[stile][h] = K^T V via MFMA; V
//            written to Vb. K never touches global memory.
// grid = 32*16 = 512 blocks (2/CU), 256 threads (4 waves as 2x2 of 64x64).
// LDS: phase 1 A+B = 64 KB; 2 blocks/CU = 128 KB < 160 KB -> occupancy kept.
// ---------------------------------------------------------------------------
__global__ __launch_bounds__(256) void kv_mfma_kernel(
    const unsigned short* __restrict__ xb,    // [4096][1024]
    const unsigned short* __restrict__ Wkvt,  // [16][128][1024]
    unsigned short* __restrict__ Vb,          // [4096][1024]
    float* __restrict__ Mpart) {              // [32][16][64][64]
  const int blk = blockIdx.x;
  const int stile = blk & 31;
  const int h = blk >> 5;
  const int s0 = stile * 128;
  const int tid = threadIdx.x;
  const int lane = tid & 63;
  const int wid = tid >> 6;
  const int wm = wid & 1, wn = wid >> 1;
  const int quad = lane >> 4, l16 = lane & 15;
  const int srow4 = lane >> 4;               // 4 rows per copy instr (256B rows)
  const int xa = l16 & 7;                    // frag-read swizzle key

  // Aliased LDS: phase 1 As+Bs (64 KB); phase 2 reuses the front as Ktl/Vtl
  // transposed tiles [64][TP_] (34 KB).
  __shared__ __align__(16) unsigned char smem[2 * 128 * BK_ * 2];
  unsigned short* As  = (unsigned short*)smem;                     // [128][128]
  unsigned short* Bs  = (unsigned short*)(smem + 128 * BK_ * 2);   // [128][128]
  unsigned short* Ktl = (unsigned short*)smem;                     // [64][TP_]
  unsigned short* Vtl = (unsigned short*)(smem + 64 * TP_ * 2);    // [64][TP_]

  float4_t acc[4][4];
  const float4_t fz = {0.f, 0.f, 0.f, 0.f};
#pragma unroll
  for (int i = 0; i < 4; ++i)
#pragma unroll
    for (int j = 0; j < 4; ++j) acc[i][j] = fz;

  for (int k0 = 0; k0 < D_; k0 += BK_) {
#pragma unroll
    for (int i = 0; i < 8; ++i) {      // A and B: 32 groups of 4 rows each
      int g = wid * 8 + i;
      int r = g * 4 + srow4;
      int ch = ((lane & 15) ^ (r & 7)) * 8;   // swizzled 16B chunk (elems)
      async_copy16(xb + (size_t)(s0 + r) * D_ + k0 + ch, As + g * 4 * BK_);
      async_copy16(Wkvt + ((size_t)h * 128 + r) * D_ + k0 + ch, Bs + g * 4 * BK_);
    }
    __syncthreads();
#pragma unroll
    for (int ks = 0; ks < 4; ++ks) {   // per-ks frag load keeps VGPRs bounded
      short8_t a[4], b[4];
#pragma unroll
      for (int mi = 0; mi < 4; ++mi)
        a[mi] = *(const short8_t*)(As + (wm * 64 + mi * 16 + l16) * BK_ +
                                   ((ks * 4 + quad) ^ xa) * 8);
#pragma unroll
      for (int ni = 0; ni < 4; ++ni)
        b[ni] = *(const short8_t*)(Bs + (wn * 64 + ni * 16 + l16) * BK_ +
                                   ((ks * 4 + quad) ^ xa) * 8);
#pragma unroll
      for (int mi = 0; mi < 4; ++mi)
#pragma unroll
        for (int ni = 0; ni < 4; ++ni)
          acc[mi][ni] = __builtin_amdgcn_mfma_f32_16x16x32_bf16(
              a[mi], b[ni], acc[mi][ni], 0, 0, 0);
    }
    __syncthreads();
  }

  // ---- phase 2a: dump quadrants transposed into LDS (bf16) ----
  // C cols: wn==0 -> K features, wn==1 -> V features.
  {
    unsigned short* dstT = (wn == 0) ? Ktl : Vtl;
#pragma unroll
    for (int mi = 0; mi < 4; ++mi)
#pragma unroll
      for (int ni = 0; ni < 4; ++ni) {
        int f = ni * 16 + l16;
        int sm = wm * 64 + mi * 16 + quad * 4;
        ushort4 o;
        o.x = f32_to_bf16(acc[mi][ni][0]);
        o.y = f32_to_bf16(acc[mi][ni][1]);
        o.z = f32_to_bf16(acc[mi][ni][2]);
        o.w = f32_to_bf16(acc[mi][ni][3]);
        *(ushort4*)&dstT[f * TP_ + sm] = o;
      }
  }
  __syncthreads();

  // ---- phase 2b: Vb[s0+s][h*64+e] from Vtl (16B stores) ----
#pragma unroll
  for (int u = 0; u < 4; ++u) {
    int unit = tid + u * 256;            // 0..1023 = 128 s x 8 e-chunks
    int s = unit & 127;
    int ec = (unit >> 7) * 8;
    union { unsigned short u16[8]; uint4 v; } t;
#pragma unroll
    for (int e = 0; e < 8; ++e) t.u16[e] = Vtl[(ec + e) * TP_ + s];
    *(uint4*)&Vb[(size_t)(s0 + s) * HD_ + h * 64 + ec] = t.v;
  }

  // ---- phase 2c: Mpart[f][e] = sum_{s<128} K[s,f] V[s,e] via MFMA ----
  {
    float4_t macc[4];
#pragma unroll
    for (int ni = 0; ni < 4; ++ni) macc[ni] = fz;
#pragma unroll
    for (int ss = 0; ss < 4; ++ss) {     // 4 k-steps of 32 s
      short8_t ka = *(const short8_t*)&Ktl[(wid * 16 + l16) * TP_ + ss * 32 + quad * 8];
#pragma unroll
      for (int ni = 0; ni < 4; ++ni) {
        short8_t vv = *(const short8_t*)&Vtl[(ni * 16 + l16) * TP_ + ss * 32 + quad * 8];
        macc[ni] = __builtin_amdgcn_mfma_f32_16x16x32_bf16(ka, vv, macc[ni], 0, 0, 0);
      }
    }
    float* mdst = Mpart + ((size_t)stile * H_ + h) * 4096;
#pragma unroll
    for (int ni = 0; ni < 4; ++ni) {
      int e = ni * 16 + l16;
#pragma unroll
      for (int r = 0; r < 4; ++r) {
        int f = wid * 16 + quad * 4 + r;
        mdst[f * 64 + e] = macc[ni][r];
      }
    }
  }
}

// ---------------------------------------------------------------------------
// m_reduce: M[b,h] = 0.125 * sum over the 16 stiles of batch b. 128 blocks.
// ---------------------------------------------------------------------------
__global__ __launch_bounds__(256) void m_reduce_kernel(
    const float* __restrict__ Mpart, float* __restrict__ M) {
  const int gid = blockIdx.x * 256 + threadIdx.x;
  const int e0 = gid * 4;               // [0, 131072)
  const int bh = e0 >> 12;              // b*16+h
  const int idx = e0 & 4095;
  const int b = bh >> 4, h = bh & 15;
  float4 s = {0.f, 0.f, 0.f, 0.f};
#pragma unroll
  for (int p = 0; p < 16; ++p) {
    const float4 v =
        *(const float4*)&Mpart[(((size_t)(b * 16 + p)) * H_ + h) * 4096 + idx];
    s.x += v.x; s.y += v.y; s.z += v.z; s.w += v.w;
  }
  s.x *= 0.125f; s.y *= 0.125f; s.z *= 0.125f; s.w *= 0.125f;
  *(float4*)&M[(size_t)bh * 4096 + idx] = s;
}

// ---------------------------------------------------------------------------
// p_kernel: P[b][h*64+f][d] = sum_e M[b,h,f,e]*Wproj[h*64+e][d], written
// TRANSPOSED as Pt[b][d][h*64+f] bf16 (k-contiguous for out_mfma staging).
// grid = B*H*(D/64) = 512 blocks.
// ---------------------------------------------------------------------------
__global__ __launch_bounds__(256) void p_kernel(
    const float* __restrict__ M, const float* __restrict__ Wproj,
    unsigned short* __restrict__ Pt) {
  const int blk = blockIdx.x;
  const int dtile = blk & 15;
  const int h = (blk >> 4) & 15;
  const int b = blk >> 8;
  const int d0 = dtile * 64;
  const int tid = threadIdx.x;
  const int tx = tid & 15, ty = tid >> 4;
  __shared__ float Ms[64][68];  // A: [e][f] (transposed on store)
  __shared__ float Ws[64][68];  // B: [e][d]
  const size_t mbase = ((size_t)(b * H_ + h)) * HS_ * HS_;
#pragma unroll
  for (int i = 0; i < 16; ++i) {
    int idx = tid + i * 256;
    int f = idx >> 6, e = idx & 63;
    Ms[e][f] = M[mbase + idx];
    Ws[f][e] = Wproj[(size_t)(h * HS_ + f) * D_ + d0 + e];
  }
  __syncthreads();
  float acc[4][4] = {};
#pragma unroll
  for (int kk = 0; kk < 64; ++kk) {
    const float4 a4 = *(const float4*)&Ms[kk][ty * 4];
    const float4 b4 = *(const float4*)&Ws[kk][tx * 4];
    const float a[4] = {a4.x, a4.y, a4.z, a4.w};
    const float bb[4] = {b4.x, b4.y, b4.z, b4.w};
#pragma unroll
    for (int i = 0; i < 4; ++i)
#pragma unroll
      for (int j = 0; j < 4; ++j) acc[i][j] += a[i] * bb[j];
  }
  // transpose through LDS: trans[d][f] then linear bf16 rows
  __syncthreads();
#pragma unroll
  for (int i = 0; i < 4; ++i)
#pragma unroll
    for (int j = 0; j < 4; ++j)
      Ms[tx * 4 + j][ty * 4 + i] = acc[i][j];
  __syncthreads();
  {
    int c = tid >> 2, ch = tid & 3;  // row c (d-dim), 16-elem chunk of f-dim
    unsigned short* dst = Pt + ((size_t)(b * D_ + d0 + c)) * HD_ + h * 64 + ch * 16;
#pragma unroll
    for (int e = 0; e < 16; ++e) dst[e] = f32_to_bf16(Ms[c][ch * 16 + e]);
  }
}

// ---------------------------------------------------------------------------
// out_mfma: out[s][d] = bproj[d] + sum_j Vb[s][j]*Pt[b][d][j].
// 128x64 tiles, grid 512 (2/CU), BK=128 (8 iters), swizzled LDS.
// 4 waves as 2(m)x2(n), each wave 64x32.   [identical to R6]
// ---------------------------------------------------------------------------
__global__ __launch_bounds__(256) void out_mfma_kernel(
    const unsigned short* __restrict__ Vb,   // [4096][1024]
    const unsigned short* __restrict__ Pt,   // [2][1024][1024]
    const float* __restrict__ bproj,
    float* __restrict__ out) {
  const int blk = blockIdx.x;
  const int ntile = blk & 15;              // 1024/64 = 16
  const int stile = blk >> 4;              // 4096/128 = 32
  const int s0 = stile * 128;
  const int n0 = ntile * 64;
  const int b = s0 >> 11;
  const int tid = threadIdx.x;
  const int lane = tid & 63;
  const int wid = tid >> 6;
  const int wm = wid & 1, wn = wid >> 1;
  const int quad = lane >> 4, l16 = lane & 15;
  const int srow4 = lane >> 4;             // 4 rows per copy instr (256B rows)
  const int xa = l16 & 7;

  __shared__ __align__(16) unsigned short As[128 * BKO_];  // 32 KB
  __shared__ __align__(16) unsigned short Bs[64 * BKO_];   // 16 KB

  float4_t acc[4][2];
  const float4_t fz = {0.f, 0.f, 0.f, 0.f};
#pragma unroll
  for (int i = 0; i < 4; ++i)
#pragma unroll
    for (int j = 0; j < 2; ++j) acc[i][j] = fz;

  const unsigned short* Bpanel = Pt + (size_t)b * D_ * HD_;
  for (int k0 = 0; k0 < HD_; k0 += BKO_) {
#pragma unroll
    for (int i = 0; i < 8; ++i) {        // A: 32 groups of 4 rows
      int g = wid * 8 + i;
      int r = g * 4 + srow4;
      int ch = ((lane & 15) ^ (r & 7)) * 8;
      async_copy16(Vb + (size_t)(s0 + r) * HD_ + k0 + ch, As + g * 4 * BKO_);
    }
#pragma unroll
    for (int i = 0; i < 4; ++i) {        // B: 16 groups of 4 rows
      int g = wid * 4 + i;
      int r = g * 4 + srow4;
      int ch = ((lane & 15) ^ (r & 7)) * 8;
      async_copy16(Bpanel + (size_t)(n0 + r) * HD_ + k0 + ch, Bs + g * 4 * BKO_);
    }
    __syncthreads();
    short8_t a[4][4], bfr[2][4];
#pragma unroll
    for (int mi = 0; mi < 4; ++mi)
#pragma unroll
      for (int ks = 0; ks < 4; ++ks)
        a[mi][ks] = *(const short8_t*)(As + (wm * 64 + mi * 16 + l16) * BKO_ +
                                       ((ks * 4 + quad) ^ xa) * 8);
#pragma unroll
    for (int ni = 0; ni < 2; ++ni)
#pragma unroll
      for (int ks = 0; ks < 4; ++ks)
        bfr[ni][ks] = *(const short8_t*)(Bs + (wn * 32 + ni * 16 + l16) * BKO_ +
                                         ((ks * 4 + quad) ^ xa) * 8);
#pragma unroll
    for (int ks = 0; ks < 4; ++ks)
#pragma unroll
      for (int mi = 0; mi < 4; ++mi)
#pragma unroll
        for (int ni = 0; ni < 2; ++ni)
          acc[mi][ni] = __builtin_amdgcn_mfma_f32_16x16x32_bf16(
              a[mi][ks], bfr[ni][ks], acc[mi][ni], 0, 0, 0);
    __syncthreads();
  }
#pragma unroll
  for (int ni = 0; ni < 2; ++ni) {
    int col = n0 + wn * 32 + ni * 16 + l16;
    float bias = bproj[col];
#pragma unroll
    for (int mi = 0; mi < 4; ++mi) {
      int rowb = s0 + wm * 64 + mi * 16 + quad * 4;
#pragma unroll
      for (int r = 0; r < 4; ++r)
        out[(size_t)(rowb + r) * D_ + col] = acc[mi][ni][r] + bias;
    }
  }
}

extern "C" void kernel_launch(void* const* d_in, const int* in_sizes, int n_in,
                              void* d_out, int out_size, void* d_ws, size_t ws_size,
                              hipStream_t stream) {
  const float* x = (const float*)d_in[0];
  const float* Wk = (const float*)d_in[1];
  const float* Wv = (const float*)d_in[2];
  const float* Wproj = (const float*)d_in[3];
  const float* bproj = (const float*)d_in[4];
  float* out = (float*)d_out;

  // Workspace layout (~32.5 MB total); every element written before read.
  char* ws = (char*)d_ws;
  unsigned short* xb = (unsigned short*)ws;                  // 4M bf16 = 8 MB
  unsigned short* Wkvt = xb + (size_t)BS_ * D_;              // 2M bf16 = 4 MB
  unsigned short* Vb = Wkvt + (size_t)H_ * 128 * D_;         // 4M bf16 = 8 MB
  float* Mpart = (float*)(Vb + (size_t)BS_ * HD_);           // 2M f32 = 8 MB  [32][16][4096]
  float* M = Mpart + (size_t)32 * H_ * 4096;                 // 128K f32 = 0.5 MB
  unsigned short* Pt = (unsigned short*)(M + (size_t)B_ * H_ * 4096);  // 2M bf16 = 4 MB

  prep_kernel<<<dim3(4096 + H_ * (D_ / 64)), dim3(256), 0, stream>>>(x, Wk, Wv, xb, Wkvt);
  kv_mfma_kernel<<<dim3(32 * H_), dim3(256), 0, stream>>>(xb, Wkvt, Vb, Mpart);
  m_reduce_kernel<<<dim3(128), dim3(256), 0, stream>>>(Mpart, M);
  p_kernel<<<dim3(B_ * H_ * (D_ / 64)), dim3(256), 0, stream>>>(M, Wproj, Pt);
  out_mfma_kernel<<<dim3(32 * 16), dim3(256), 0, stream>>>(Vb, Pt, bproj, out);
}